// Round 2
// baseline (7167.716 us; speedup 1.0000x reference)
//
#include <hip/hip_runtime.h>
#include <stdint.h>

#define NTOK 1569
#define BB 8
#define CC 768
#define HH 12
#define HD 64
#define NBH (BB*HH)          // 96
#define NCHUNK 25            // ceil(1569/64)

static const size_t SZ = (size_t)NBH * NTOK * HD;   // 9,639,936 elements per [B,H,N,hd]

using f32x4 = __attribute__((ext_vector_type(4))) float;
using i32x4 = __attribute__((ext_vector_type(4))) int;
using bfrag = __attribute__((ext_vector_type(8))) short;

__device__ __forceinline__ float bf2f(short s){
  return __uint_as_float(((uint32_t)(uint16_t)s) << 16);
}
__device__ __forceinline__ short f2bf(float f){
  uint32_t u = __float_as_uint(f);
  uint32_t r = (u + 0x7FFFu + ((u >> 16) & 1u)) >> 16;
  return (short)r;
}

// ---------------------------------------------------------------------------
// pre[b] = sum_n ||x[n,b,:]||_2   (fp32 input; mean & *scale folded in later)
// ---------------------------------------------------------------------------
__global__ __launch_bounds__(256) void prenorm_kernel(const float* __restrict__ x,
                                                      float* __restrict__ pre)
{
  const int b = blockIdx.y;
  const int wave = threadIdx.x >> 6, lane = threadIdx.x & 63;
  const int g = blockIdx.x * 4 + wave;          // [0, 200)
  float local = 0.f;
  for (int n = g; n < NTOK; n += 200){
    const float* xp = x + ((size_t)n * BB + b) * CC + lane * 4;
    float ss = 0.f;
    #pragma unroll
    for (int e = 0; e < 3; e++){                // 768 floats = 3 x (64 lanes x 4)
      f32x4 vv = *(const f32x4*)(xp + 256*e);
      ss += vv[0]*vv[0] + vv[1]*vv[1] + vv[2]*vv[2] + vv[3]*vv[3];
    }
    #pragma unroll
    for (int off = 1; off < 64; off <<= 1) ss += __shfl_xor(ss, off);
    local += sqrtf(ss);
  }
  if (lane == 0) atomicAdd(&pre[b], local);
}

// split a fp32 octet into hi/lo bf16 octets
__device__ __forceinline__ void split8(f32x4 f0, f32x4 f1, i32x4* hi, i32x4* lo){
  union { short s[8]; i32x4 v; } uh, ul;
  #pragma unroll
  for (int e = 0; e < 4; e++){
    short h0 = f2bf(f0[e]); uh.s[e]   = h0; ul.s[e]   = f2bf(f0[e] - bf2f(h0));
    short h1 = f2bf(f1[e]); uh.s[4+e] = h1; ul.s[4+e] = f2bf(f1[e] - bf2f(h1));
  }
  *hi = uh.v; *lo = ul.v;
}

// ---------------------------------------------------------------------------
// qkv GEMM (fp32 in, fp32-grade accuracy via bf16 hi/lo split MFMA):
//   out[b,n,j] = sum_c x[n,b,c] * Wqkv[j,c];  scatter to q/k/v fp32 [B,H,N,hd]
// grid: (25 mtiles, 36 jtiles, 8 b), block 256
// ---------------------------------------------------------------------------
__global__ __launch_bounds__(256) void qkv_gemm(const float* __restrict__ x,
                                                const float* __restrict__ w,
                                                float* __restrict__ q,
                                                float* __restrict__ k,
                                                float* __restrict__ v)
{
  __shared__ short Ah[2048], Al[2048], Bh[2048], Bl[2048];   // [kquad][row][8]

  const int b = blockIdx.z, mt = blockIdx.x, jt = blockIdx.y;
  const int tid = threadIdx.x;
  const int row = tid >> 2, quad = tid & 3;
  int n_ld = mt*64 + row; if (n_ld > NTOK-1) n_ld = NTOK-1;
  const float* aptr = x + ((size_t)n_ld * BB + b) * CC + quad*8;
  const float* bptr = w + (size_t)(jt*64 + row) * CC + quad*8;

  const int lane = tid & 63, w4 = tid >> 6;
  const int r0 = (w4 >> 1) * 32, c0 = (w4 & 1) * 32;
  const int l16 = lane & 15, lq = lane >> 4;
  const int slot = (quad*64 + row)*8;

  f32x4 acc[2][2] = {};
  for (int kt = 0; kt < 24; kt++){
    i32x4 hi, lo;
    split8(*(const f32x4*)(aptr + kt*32), *(const f32x4*)(aptr + kt*32 + 4), &hi, &lo);
    *(i32x4*)&Ah[slot] = hi; *(i32x4*)&Al[slot] = lo;
    split8(*(const f32x4*)(bptr + kt*32), *(const f32x4*)(bptr + kt*32 + 4), &hi, &lo);
    *(i32x4*)&Bh[slot] = hi; *(i32x4*)&Bl[slot] = lo;
    __syncthreads();
    const int ia0 = (lq*64 + r0 +      l16)*8, ia1 = (lq*64 + r0 + 16 + l16)*8;
    const int ib0 = (lq*64 + c0 +      l16)*8, ib1 = (lq*64 + c0 + 16 + l16)*8;
    bfrag ah[2] = { *(const bfrag*)&Ah[ia0], *(const bfrag*)&Ah[ia1] };
    bfrag al[2] = { *(const bfrag*)&Al[ia0], *(const bfrag*)&Al[ia1] };
    bfrag bh[2] = { *(const bfrag*)&Bh[ib0], *(const bfrag*)&Bh[ib1] };
    bfrag bl[2] = { *(const bfrag*)&Bl[ib0], *(const bfrag*)&Bl[ib1] };
    #pragma unroll
    for (int i = 0; i < 2; i++)
      #pragma unroll
      for (int j = 0; j < 2; j++){
        acc[i][j] = __builtin_amdgcn_mfma_f32_16x16x32_bf16(ah[i], bh[j], acc[i][j], 0, 0, 0);
        acc[i][j] = __builtin_amdgcn_mfma_f32_16x16x32_bf16(ah[i], bl[j], acc[i][j], 0, 0, 0);
        acc[i][j] = __builtin_amdgcn_mfma_f32_16x16x32_bf16(al[i], bh[j], acc[i][j], 0, 0, 0);
      }
    __syncthreads();
  }

  const int s = jt / 12, h = jt % 12;
  float* outp = (s == 0) ? q : (s == 1) ? k : v;
  const size_t obase = (size_t)(b*HH + h) * NTOK * HD;
  #pragma unroll
  for (int i = 0; i < 2; i++)
    #pragma unroll
    for (int j = 0; j < 2; j++){
      const int d = c0 + j*16 + l16;
      #pragma unroll
      for (int r = 0; r < 4; r++){
        const int m = mt*64 + r0 + i*16 + lq*4 + r;
        if (m < NTOK) outp[obase + (size_t)m*HD + d] = acc[i][j][r];
      }
    }
}

// ---------------------------------------------------------------------------
// proj GEMM (hi/lo split MFMA): out[n,b,co] = sum_c (in[b,h,n,d]*scl) * Wproj[co,c] + bproj[co]
// in: fp32 [B,H,N,hd]; out: fp32 [N,B,C]
// grid: (25, 12, 8), block 256
// ---------------------------------------------------------------------------
__global__ __launch_bounds__(256) void proj_gemm(const float* __restrict__ in,
                                                 const float* __restrict__ w,
                                                 const float* __restrict__ bias,
                                                 float* __restrict__ outp,
                                                 float scl)
{
  __shared__ short Ah[2048], Al[2048], Bh[2048], Bl[2048];

  const int b = blockIdx.z, mt = blockIdx.x, jt = blockIdx.y;
  const int tid = threadIdx.x;
  const int row = tid >> 2, quad = tid & 3;
  int n_ld = mt*64 + row; if (n_ld > NTOK-1) n_ld = NTOK-1;

  const int lane = tid & 63, w4 = tid >> 6;
  const int r0 = (w4 >> 1) * 32, c0 = (w4 & 1) * 32;
  const int l16 = lane & 15, lq = lane >> 4;
  const int slot = (quad*64 + row)*8;
  const float* bptr = w + (size_t)(jt*64 + row) * CC + quad*8;

  f32x4 acc[2][2] = {};
  for (int kt = 0; kt < 24; kt++){
    const int kk = kt*32 + quad*8;
    const int h = kk >> 6, d = kk & 63;
    const float* ap = in + ((size_t)(b*HH + h) * NTOK + n_ld) * HD + d;
    f32x4 f0 = *(const f32x4*)ap * scl;
    f32x4 f1 = *(const f32x4*)(ap + 4) * scl;
    i32x4 hi, lo;
    split8(f0, f1, &hi, &lo);
    *(i32x4*)&Ah[slot] = hi; *(i32x4*)&Al[slot] = lo;
    split8(*(const f32x4*)(bptr + kt*32), *(const f32x4*)(bptr + kt*32 + 4), &hi, &lo);
    *(i32x4*)&Bh[slot] = hi; *(i32x4*)&Bl[slot] = lo;
    __syncthreads();
    const int ia0 = (lq*64 + r0 +      l16)*8, ia1 = (lq*64 + r0 + 16 + l16)*8;
    const int ib0 = (lq*64 + c0 +      l16)*8, ib1 = (lq*64 + c0 + 16 + l16)*8;
    bfrag ah[2] = { *(const bfrag*)&Ah[ia0], *(const bfrag*)&Ah[ia1] };
    bfrag al[2] = { *(const bfrag*)&Al[ia0], *(const bfrag*)&Al[ia1] };
    bfrag bh[2] = { *(const bfrag*)&Bh[ib0], *(const bfrag*)&Bh[ib1] };
    bfrag bl[2] = { *(const bfrag*)&Bl[ib0], *(const bfrag*)&Bl[ib1] };
    #pragma unroll
    for (int i = 0; i < 2; i++)
      #pragma unroll
      for (int j = 0; j < 2; j++){
        acc[i][j] = __builtin_amdgcn_mfma_f32_16x16x32_bf16(ah[i], bh[j], acc[i][j], 0, 0, 0);
        acc[i][j] = __builtin_amdgcn_mfma_f32_16x16x32_bf16(ah[i], bl[j], acc[i][j], 0, 0, 0);
        acc[i][j] = __builtin_amdgcn_mfma_f32_16x16x32_bf16(al[i], bh[j], acc[i][j], 0, 0, 0);
      }
    __syncthreads();
  }

  #pragma unroll
  for (int i = 0; i < 2; i++)
    #pragma unroll
    for (int j = 0; j < 2; j++){
      const int co = jt*64 + c0 + j*16 + l16;
      const float bv = bias[co];
      #pragma unroll
      for (int r = 0; r < 4; r++){
        const int m = mt*64 + r0 + i*16 + lq*4 + r;
        if (m < NTOK) outp[((size_t)m*BB + b)*CC + co] = acc[i][j][r] + bv;
      }
    }
}

// ---------------------------------------------------------------------------
// per-vector l2 normalize (fp32): one wave per 64-elem vector
// ---------------------------------------------------------------------------
__global__ __launch_bounds__(256) void l2norm_kernel(const float* __restrict__ in,
                                                     float* __restrict__ out)
{
  const int vec = blockIdx.x * 4 + (threadIdx.x >> 6);
  const int lane = threadIdx.x & 63;
  if (vec >= NBH * NTOK) return;
  const size_t idx = (size_t)vec * HD + lane;
  const float vv = in[idx];
  float ss = vv * vv;
  #pragma unroll
  for (int off = 1; off < 64; off <<= 1) ss += __shfl_xor(ss, off);
  const float den = fmaxf(sqrtf(ss), 1e-12f);
  out[idx] = vv / den;
}

// ---------------------------------------------------------------------------
// Flash-style fp32 attention: Out[b,h,n,:] (+)= softmax_m(X[n,:]·Y[m,:]*temp) @ Z
// 64 query rows / block, 64-col key chunks, online softmax.
// Thread (R=tid/16, Cg=tid%16): rows r0=R*4..+3, S-cols/out-dims Cg*4..+3.
// LDS: Xs (Q), YP (K^T then P), Zs (V) -> 52.2 KB
// grid: (25, 96), block 256
// ---------------------------------------------------------------------------
__global__ __launch_bounds__(256) void attn_kernel(
    const float* __restrict__ X, const float* __restrict__ Y, const float* __restrict__ Z,
    float* __restrict__ Out, const float* __restrict__ pre, float tf, int accum)
{
  __shared__ float Xs[64][68];
  __shared__ float YP[64][68];
  __shared__ float Zs[64][68];

  const int bh = blockIdx.y;
  const int b  = bh / HH;
  const float temp = pre ? pre[b] * tf : tf;
  const size_t base = (size_t)bh * NTOK * HD;
  const int row0 = blockIdx.x * 64;
  const int tid = threadIdx.x;
  const int R = tid >> 4, Cg = tid & 15;
  const int r0 = R * 4, c0 = Cg * 4, d0 = Cg * 4;
  const int rr = tid >> 2, seg = tid & 3;

  { // stage Q tile (64 rows x 64 dims)
    int n = row0 + rr; if (n > NTOK-1) n = NTOK-1;
    const float* xp = X + base + (size_t)n * HD + seg*16;
    #pragma unroll
    for (int qq = 0; qq < 4; qq++)
      *(f32x4*)&Xs[rr][seg*16 + qq*4] = *(const f32x4*)(xp + qq*4);
  }

  float M[4], l[4];
  f32x4 a[4];
  #pragma unroll
  for (int i = 0; i < 4; i++){ M[i] = -__builtin_inff(); l[i] = 0.f; a[i] = (f32x4)0.f; }

  for (int ch = 0; ch < NCHUNK; ch++){
    { // stage K tile transposed (YP[d][m]) and V tile (Zs[m][d])
      const int mg = ch*64 + rr;
      const int ms = mg > NTOK-1 ? NTOK-1 : mg;
      const float* yp = Y + base + (size_t)ms * HD + seg*16;
      const float* zp = Z + base + (size_t)ms * HD + seg*16;
      #pragma unroll
      for (int qq = 0; qq < 4; qq++){
        f32x4 yv = *(const f32x4*)(yp + qq*4);
        const int db = seg*16 + qq*4;
        YP[db+0][rr] = yv[0]; YP[db+1][rr] = yv[1];
        YP[db+2][rr] = yv[2]; YP[db+3][rr] = yv[3];
        *(f32x4*)&Zs[rr][seg*16 + qq*4] = *(const f32x4*)(zp + qq*4);
      }
    }
    __syncthreads();

    // S = Q·K^T for this thread's 4x4 sub-block
    f32x4 s[4];
    #pragma unroll
    for (int i = 0; i < 4; i++) s[i] = (f32x4)0.f;
    #pragma unroll
    for (int dc = 0; dc < 16; dc++){
      f32x4 y0 = *(const f32x4*)&YP[dc*4+0][c0];
      f32x4 y1 = *(const f32x4*)&YP[dc*4+1][c0];
      f32x4 y2 = *(const f32x4*)&YP[dc*4+2][c0];
      f32x4 y3 = *(const f32x4*)&YP[dc*4+3][c0];
      #pragma unroll
      for (int i = 0; i < 4; i++){
        f32x4 xv = *(const f32x4*)&Xs[r0+i][dc*4];
        s[i] += y0 * xv[0];
        s[i] += y1 * xv[1];
        s[i] += y2 * xv[2];
        s[i] += y3 * xv[3];
      }
    }
    __syncthreads();   // all waves done reading YP as K-tile

    // online softmax update per row; stash P rows into YP (same quarter-wave rows)
    #pragma unroll
    for (int i = 0; i < 4; i++){
      f32x4 sm;
      #pragma unroll
      for (int j = 0; j < 4; j++){
        const int col = ch*64 + c0 + j;
        sm[j] = (col < NTOK) ? s[i][j] * temp : -__builtin_inff();
      }
      float mx = fmaxf(fmaxf(sm[0], sm[1]), fmaxf(sm[2], sm[3]));
      #pragma unroll
      for (int off = 1; off < 16; off <<= 1)
        mx = fmaxf(mx, __shfl_xor(mx, off));
      const float Mn = fmaxf(M[i], mx);
      const float al = __expf(M[i] - Mn);
      f32x4 p;
      float rs = 0.f;
      #pragma unroll
      for (int j = 0; j < 4; j++){ p[j] = __expf(sm[j] - Mn); rs += p[j]; }
      #pragma unroll
      for (int off = 1; off < 16; off <<= 1)
        rs += __shfl_xor(rs, off);
      l[i] = l[i]*al + rs;
      M[i] = Mn;
      a[i] *= al;
      *(f32x4*)&YP[r0+i][c0] = p;
    }

    // PV accumulate: a[i][d0..+3] += sum_m P[r0+i][m] * V[m][d0..+3]
    #pragma unroll 4
    for (int m = 0; m < 64; m++){
      f32x4 zv = *(const f32x4*)&Zs[m][d0];
      const float p0 = YP[r0+0][m], p1 = YP[r0+1][m];
      const float p2 = YP[r0+2][m], p3 = YP[r0+3][m];
      a[0] += zv * p0; a[1] += zv * p1; a[2] += zv * p2; a[3] += zv * p3;
    }
    __syncthreads();   // done with Zs / YP before next restage
  }

  #pragma unroll
  for (int i = 0; i < 4; i++){
    const int n = row0 + r0 + i;
    if (n < NTOK){
      const float inv = 1.0f / l[i];
      f32x4 o = a[i] * inv;
      const size_t idx = base + (size_t)n*HD + d0;
      if (accum) o += *(const f32x4*)&Out[idx];
      *(f32x4*)&Out[idx] = o;
    }
  }
}

// ---------------------------------------------------------------------------
extern "C" void kernel_launch(void* const* d_in, const int* in_sizes, int n_in,
                              void* d_out, int out_size, void* d_ws, size_t ws_size,
                              hipStream_t stream)
{
  (void)in_sizes; (void)n_in; (void)out_size; (void)ws_size;

  const float* x     = (const float*)d_in[0];   // fp32 [N,B,C]
  const float* wqkv  = (const float*)d_in[1];   // fp32 [2304,768]
  const float* wproj = (const float*)d_in[2];   // fp32 [768,768]
  const float* bias  = (const float*)d_in[3];   // fp32 [768]
  float* out = (float*)d_out;                   // fp32: [x_out | x_ori], each [N,B,C]

  float* ws = (float*)d_ws;
  float* q   = ws;          // later reused as branch accumulator (branch q runs first)
  float* k   = q   + SZ;
  float* v   = k   + SZ;
  float* xh  = v   + SZ;
  float* y   = xh  + SZ;
  float* pre = y   + SZ;    // 8 floats
  float* acc = q;           // alias: q is dead once l2norm(q) has run

  hipMemsetAsync(pre, 0, BB * sizeof(float), stream);

  prenorm_kernel<<<dim3(50, 8), 256, 0, stream>>>(x, pre);
  qkv_gemm<<<dim3(25, 36, 8), 256, 0, stream>>>(x, wqkv, q, k, v);

  const float SCALE = 0.125f;                 // hd^-0.5
  const float FACT  = SCALE / (float)NTOK;    // inv_temp = pre[b] * FACT

  // original attention -> x_ori (second output)
  attn_kernel<<<dim3(25, 96), 256, 0, stream>>>(q, k, v, y, nullptr, SCALE, 0);
  proj_gemm<<<dim3(25, 12, 8), 256, 0, stream>>>(y, wproj, bias,
      out + (size_t)NTOK * BB * CC, 1.0f);

  // self-self branches over {q, k, v} (q first so its buffer can become acc)
  const float* srcs[3] = { q, k, v };
  for (int sI = 0; sI < 3; sI++){
    l2norm_kernel<<<37656, 256, 0, stream>>>(srcs[sI], xh);
    attn_kernel<<<dim3(25, 96), 256, 0, stream>>>(xh, xh, xh, y, pre, FACT, 0);
    l2norm_kernel<<<37656, 256, 0, stream>>>(y, xh);
    attn_kernel<<<dim3(25, 96), 256, 0, stream>>>(xh, xh, v, acc, pre, FACT, sI == 0 ? 0 : 1);
  }

  // (sum of branches)/3 -> proj -> x_out (first output)
  proj_gemm<<<dim3(25, 12, 8), 256, 0, stream>>>(acc, wproj, bias, out, 1.0f / 3.0f);
}

// Round 3
// 2258.776 us; speedup vs baseline: 3.1733x; 3.1733x over previous
//
#include <hip/hip_runtime.h>
#include <stdint.h>

#define NTOK 1569
#define BB 8
#define CC 768
#define HH 12
#define HD 64
#define NBH (BB*HH)          // 96
#define NCHUNK 25            // ceil(1569/64) key chunks
#define NVEC (NBH*NTOK)      // 150624 head-vectors

typedef unsigned short ushort_t;
static const size_t SZ = (size_t)NBH * NTOK * HD;   // 9,639,936 elements per [B,H,N,hd]

using f32x4 = __attribute__((ext_vector_type(4))) float;
using i32x4 = __attribute__((ext_vector_type(4))) int;
using bfrag = __attribute__((ext_vector_type(8))) short;

__device__ __forceinline__ float bf2f(ushort_t s){
  return __uint_as_float(((uint32_t)s) << 16);
}
__device__ __forceinline__ ushort_t f2bf(float f){
  uint32_t u = __float_as_uint(f);
  uint32_t r = (u + 0x7FFFu + ((u >> 16) & 1u)) >> 16;
  return (ushort_t)r;
}

// ---------------------------------------------------------------------------
// pre[b] = sum_n ||x[n,b,:]||_2   (fp32 input; mean & *scale folded in later)
// ---------------------------------------------------------------------------
__global__ __launch_bounds__(256) void prenorm_kernel(const float* __restrict__ x,
                                                      float* __restrict__ pre)
{
  const int b = blockIdx.y;
  const int wave = threadIdx.x >> 6, lane = threadIdx.x & 63;
  const int g = blockIdx.x * 4 + wave;          // [0, 200)
  float local = 0.f;
  for (int n = g; n < NTOK; n += 200){
    const float* xp = x + ((size_t)n * BB + b) * CC + lane * 4;
    float ss = 0.f;
    #pragma unroll
    for (int e = 0; e < 3; e++){
      f32x4 vv = *(const f32x4*)(xp + 256*e);
      ss += vv[0]*vv[0] + vv[1]*vv[1] + vv[2]*vv[2] + vv[3]*vv[3];
    }
    #pragma unroll
    for (int off = 1; off < 64; off <<= 1) ss += __shfl_xor(ss, off);
    local += sqrtf(ss);
  }
  if (lane == 0) atomicAdd(&pre[b], local);
}

// split a fp32 octet into hi/lo bf16 octets (fp32-grade MFMA accuracy)
__device__ __forceinline__ void split8(f32x4 f0, f32x4 f1, i32x4* hi, i32x4* lo){
  union { ushort_t s[8]; i32x4 v; } uh, ul;
  #pragma unroll
  for (int e = 0; e < 4; e++){
    ushort_t h0 = f2bf(f0[e]); uh.s[e]   = h0; ul.s[e]   = f2bf(f0[e] - bf2f(h0));
    ushort_t h1 = f2bf(f1[e]); uh.s[4+e] = h1; ul.s[4+e] = f2bf(f1[e] - bf2f(h1));
  }
  *hi = uh.v; *lo = ul.v;
}

// ---------------------------------------------------------------------------
// qkv GEMM (hi/lo split MFMA): out[b,n,j] = sum_c x[n,b,c]*Wqkv[j,c]
// outputs bf16 qb/kb/vb [B,H,N,hd]
// grid: (25, 36, 8), block 256
// ---------------------------------------------------------------------------
__global__ __launch_bounds__(256) void qkv_gemm(const float* __restrict__ x,
                                                const float* __restrict__ w,
                                                ushort_t* __restrict__ qb,
                                                ushort_t* __restrict__ kb,
                                                ushort_t* __restrict__ vb)
{
  __shared__ ushort_t Ah[2048], Al[2048], Bh[2048], Bl[2048];   // [kquad][row][8]

  const int b = blockIdx.z, mt = blockIdx.x, jt = blockIdx.y;
  const int tid = threadIdx.x;
  const int row = tid >> 2, quad = tid & 3;
  int n_ld = mt*64 + row; if (n_ld > NTOK-1) n_ld = NTOK-1;
  const float* aptr = x + ((size_t)n_ld * BB + b) * CC + quad*8;
  const float* bptr = w + (size_t)(jt*64 + row) * CC + quad*8;

  const int lane = tid & 63, w4 = tid >> 6;
  const int r0 = (w4 >> 1) * 32, c0 = (w4 & 1) * 32;
  const int l16 = lane & 15, lq = lane >> 4;
  const int slot = (quad*64 + row)*8;

  f32x4 acc[2][2] = {};
  for (int kt = 0; kt < 24; kt++){
    i32x4 hi, lo;
    split8(*(const f32x4*)(aptr + kt*32), *(const f32x4*)(aptr + kt*32 + 4), &hi, &lo);
    *(i32x4*)&Ah[slot] = hi; *(i32x4*)&Al[slot] = lo;
    split8(*(const f32x4*)(bptr + kt*32), *(const f32x4*)(bptr + kt*32 + 4), &hi, &lo);
    *(i32x4*)&Bh[slot] = hi; *(i32x4*)&Bl[slot] = lo;
    __syncthreads();
    const int ia0 = (lq*64 + r0 +      l16)*8, ia1 = (lq*64 + r0 + 16 + l16)*8;
    const int ib0 = (lq*64 + c0 +      l16)*8, ib1 = (lq*64 + c0 + 16 + l16)*8;
    bfrag ah[2] = { *(const bfrag*)&Ah[ia0], *(const bfrag*)&Ah[ia1] };
    bfrag al[2] = { *(const bfrag*)&Al[ia0], *(const bfrag*)&Al[ia1] };
    bfrag bh[2] = { *(const bfrag*)&Bh[ib0], *(const bfrag*)&Bh[ib1] };
    bfrag bl[2] = { *(const bfrag*)&Bl[ib0], *(const bfrag*)&Bl[ib1] };
    #pragma unroll
    for (int i = 0; i < 2; i++)
      #pragma unroll
      for (int j = 0; j < 2; j++){
        acc[i][j] = __builtin_amdgcn_mfma_f32_16x16x32_bf16(ah[i], bh[j], acc[i][j], 0, 0, 0);
        acc[i][j] = __builtin_amdgcn_mfma_f32_16x16x32_bf16(ah[i], bl[j], acc[i][j], 0, 0, 0);
        acc[i][j] = __builtin_amdgcn_mfma_f32_16x16x32_bf16(al[i], bh[j], acc[i][j], 0, 0, 0);
      }
    __syncthreads();
  }

  const int s = jt / 12, h = jt % 12;
  ushort_t* outp = (s == 0) ? qb : (s == 1) ? kb : vb;
  const size_t obase = (size_t)(b*HH + h) * NTOK * HD;
  #pragma unroll
  for (int i = 0; i < 2; i++)
    #pragma unroll
    for (int j = 0; j < 2; j++){
      const int d = c0 + j*16 + l16;
      #pragma unroll
      for (int r = 0; r < 4; r++){
        const int m = mt*64 + r0 + i*16 + lq*4 + r;
        if (m < NTOK) outp[obase + (size_t)m*HD + d] = f2bf(acc[i][j][r]);
      }
    }
}

// ---------------------------------------------------------------------------
// proj GEMM (hi/lo split MFMA): out[n,b,co] = sum_c (in[b,h,n,d]*scl)*Wproj[co,c] + bproj[co]
// in fp32 [B,H,N,hd]; out fp32 [N,B,C]
// ---------------------------------------------------------------------------
__global__ __launch_bounds__(256) void proj_gemm(const float* __restrict__ in,
                                                 const float* __restrict__ w,
                                                 const float* __restrict__ bias,
                                                 float* __restrict__ outp,
                                                 float scl)
{
  __shared__ ushort_t Ah[2048], Al[2048], Bh[2048], Bl[2048];

  const int b = blockIdx.z, mt = blockIdx.x, jt = blockIdx.y;
  const int tid = threadIdx.x;
  const int row = tid >> 2, quad = tid & 3;
  int n_ld = mt*64 + row; if (n_ld > NTOK-1) n_ld = NTOK-1;

  const int lane = tid & 63, w4 = tid >> 6;
  const int r0 = (w4 >> 1) * 32, c0 = (w4 & 1) * 32;
  const int l16 = lane & 15, lq = lane >> 4;
  const int slot = (quad*64 + row)*8;
  const float* bptr = w + (size_t)(jt*64 + row) * CC + quad*8;

  f32x4 acc[2][2] = {};
  for (int kt = 0; kt < 24; kt++){
    const int kk = kt*32 + quad*8;
    const int h = kk >> 6, d = kk & 63;
    const float* ap = in + ((size_t)(b*HH + h) * NTOK + n_ld) * HD + d;
    f32x4 f0 = *(const f32x4*)ap * scl;
    f32x4 f1 = *(const f32x4*)(ap + 4) * scl;
    i32x4 hi, lo;
    split8(f0, f1, &hi, &lo);
    *(i32x4*)&Ah[slot] = hi; *(i32x4*)&Al[slot] = lo;
    split8(*(const f32x4*)(bptr + kt*32), *(const f32x4*)(bptr + kt*32 + 4), &hi, &lo);
    *(i32x4*)&Bh[slot] = hi; *(i32x4*)&Bl[slot] = lo;
    __syncthreads();
    const int ia0 = (lq*64 + r0 +      l16)*8, ia1 = (lq*64 + r0 + 16 + l16)*8;
    const int ib0 = (lq*64 + c0 +      l16)*8, ib1 = (lq*64 + c0 + 16 + l16)*8;
    bfrag ah[2] = { *(const bfrag*)&Ah[ia0], *(const bfrag*)&Ah[ia1] };
    bfrag al[2] = { *(const bfrag*)&Al[ia0], *(const bfrag*)&Al[ia1] };
    bfrag bh[2] = { *(const bfrag*)&Bh[ib0], *(const bfrag*)&Bh[ib1] };
    bfrag bl[2] = { *(const bfrag*)&Bl[ib0], *(const bfrag*)&Bl[ib1] };
    #pragma unroll
    for (int i = 0; i < 2; i++)
      #pragma unroll
      for (int j = 0; j < 2; j++){
        acc[i][j] = __builtin_amdgcn_mfma_f32_16x16x32_bf16(ah[i], bh[j], acc[i][j], 0, 0, 0);
        acc[i][j] = __builtin_amdgcn_mfma_f32_16x16x32_bf16(ah[i], bl[j], acc[i][j], 0, 0, 0);
        acc[i][j] = __builtin_amdgcn_mfma_f32_16x16x32_bf16(al[i], bh[j], acc[i][j], 0, 0, 0);
      }
    __syncthreads();
  }

  #pragma unroll
  for (int i = 0; i < 2; i++)
    #pragma unroll
    for (int j = 0; j < 2; j++){
      const int co = jt*64 + c0 + j*16 + l16;
      const float bv = bias[co];
      #pragma unroll
      for (int r = 0; r < 4; r++){
        const int m = mt*64 + r0 + i*16 + lq*4 + r;
        if (m < NTOK) outp[((size_t)m*BB + b)*CC + co] = acc[i][j][r] + bv;
      }
    }
}

// ---------------------------------------------------------------------------
// l2 normalize: 32 lanes per 64-elem vector (2 elems/lane, packed bf16 I/O).
// Input either bf16 (inb) or fp32 (inf_); output bf16.
// ---------------------------------------------------------------------------
__global__ __launch_bounds__(256) void l2norm_kernel(const ushort_t* __restrict__ inb,
                                                     const float* __restrict__ inf_,
                                                     ushort_t* __restrict__ outb)
{
  const int vec = blockIdx.x * 8 + (threadIdx.x >> 5);
  const int lane = threadIdx.x & 31;
  if (vec >= NVEC) return;
  const size_t idx = (size_t)vec * HD + lane * 2;
  float a, c;
  if (inb){
    uint32_t pk = *(const uint32_t*)(inb + idx);
    a = bf2f((ushort_t)(pk & 0xFFFF));
    c = bf2f((ushort_t)(pk >> 16));
  } else {
    a = inf_[idx]; c = inf_[idx + 1];
  }
  float ss = a*a + c*c;
  #pragma unroll
  for (int off = 1; off < 32; off <<= 1) ss += __shfl_xor(ss, off);
  const float inv = 1.0f / fmaxf(sqrtf(ss), 1e-12f);
  uint32_t pk = (uint32_t)f2bf(a * inv) | ((uint32_t)f2bf(c * inv) << 16);
  *(uint32_t*)(outb + idx) = pk;
}

// ---------------------------------------------------------------------------
// MFMA flash attention: Out[b,h,n,:] (+)= softmax_m(X[n,:]·Y[m,:]*temp) @ Z
// bf16 inputs [B,H,N,64], fp32 out. 128 query rows/block (4 waves x 32 rows),
// 64-key chunks. Q A-frags in regs; K natural + V^T staged in LDS; P via LDS
// round-trip (C-layout -> A-layout). Online softmax state per-lane (rows =
// 4*lq+reg of C-layout == softmax ownership).
// LDS: Ks[64][72] + Vt[64][72] + Ps[128][72] bf16 = 36.9 KB
// grid: (13, 96), block 256
// ---------------------------------------------------------------------------
__global__ __launch_bounds__(256) void attn_mfma(
    const ushort_t* __restrict__ X, const ushort_t* __restrict__ Y,
    const ushort_t* __restrict__ Z, float* __restrict__ Out,
    const float* __restrict__ pre, float tf, int accum)
{
  __shared__ ushort_t Ks[64][72];
  __shared__ ushort_t Vt[64][72];
  __shared__ ushort_t Ps[128][72];

  const int bh = blockIdx.y, b = bh / HH;
  const float temp = pre ? pre[b] * tf : tf;
  const size_t base = (size_t)bh * NTOK * HD;
  const int row0 = blockIdx.x * 128;
  const int tid = threadIdx.x;
  const int w = tid >> 6, lane = tid & 63;
  const int l16 = lane & 15, lq = lane >> 4;

  // Q fragments: rows row0 + w*32 + rt*16 + l16, k = lq*8 + 32*ks
  bfrag qf[2][2];
  #pragma unroll
  for (int rt = 0; rt < 2; rt++){
    int r = row0 + w*32 + rt*16 + l16; if (r > NTOK-1) r = NTOK-1;
    const ushort_t* qp = X + base + (size_t)r*HD + lq*8;
    qf[rt][0] = *(const bfrag*)qp;
    qf[rt][1] = *(const bfrag*)(qp + 32);
  }

  // staging assignments
  const int skey = tid >> 2, sseg = tid & 3;          // K: key row, 2x8 bf16 chunks
  const int vd0 = (tid & 7) * 8, vk0 = (tid >> 3) * 2; // V^T: 8 d-rows x 2 keys

  f32x4 acc[2][4] = {};
  float M[2][4], l[2][4];
  #pragma unroll
  for (int rt = 0; rt < 2; rt++)
    #pragma unroll
    for (int r = 0; r < 4; r++){ M[rt][r] = -__builtin_inff(); l[rt][r] = 0.f; }

  for (int ch = 0; ch < NCHUNK; ch++){
    { // stage K (natural) and V (transposed)
      int kg = ch*64 + skey; if (kg > NTOK-1) kg = NTOK-1;
      const ushort_t* kp = Y + base + (size_t)kg*HD + sseg*8;
      *(i32x4*)&Ks[skey][sseg*8]      = *(const i32x4*)kp;
      *(i32x4*)&Ks[skey][sseg*8 + 32] = *(const i32x4*)(kp + 32);

      int vg0 = ch*64 + vk0, vg1 = vg0 + 1;
      if (vg0 > NTOK-1) vg0 = NTOK-1;
      if (vg1 > NTOK-1) vg1 = NTOK-1;
      bfrag za = *(const bfrag*)(Z + base + (size_t)vg0*HD + vd0);
      bfrag zb = *(const bfrag*)(Z + base + (size_t)vg1*HD + vd0);
      #pragma unroll
      for (int e = 0; e < 8; e++){
        uint32_t pk = ((uint32_t)(uint16_t)za[e]) | (((uint32_t)(uint16_t)zb[e]) << 16);
        *(uint32_t*)&Vt[vd0 + e][vk0] = pk;
      }
    }
    __syncthreads();

    // S = Q·K^T  (C rows = 4*lq+reg, cols = j*16+l16)
    f32x4 s[2][4] = {};
    #pragma unroll
    for (int ks = 0; ks < 2; ks++){
      #pragma unroll
      for (int j = 0; j < 4; j++){
        bfrag kbf = *(const bfrag*)&Ks[j*16 + l16][lq*8 + 32*ks];
        s[0][j] = __builtin_amdgcn_mfma_f32_16x16x32_bf16(qf[0][ks], kbf, s[0][j], 0, 0, 0);
        s[1][j] = __builtin_amdgcn_mfma_f32_16x16x32_bf16(qf[1][ks], kbf, s[1][j], 0, 0, 0);
      }
    }

    // online softmax + P -> LDS (bf16)
    #pragma unroll
    for (int rt = 0; rt < 2; rt++){
      #pragma unroll
      for (int r = 0; r < 4; r++){
        float sm[4];
        #pragma unroll
        for (int j = 0; j < 4; j++){
          const int col = ch*64 + j*16 + l16;
          sm[j] = (col < NTOK) ? s[rt][j][r] * temp : -__builtin_inff();
        }
        float mx = fmaxf(fmaxf(sm[0], sm[1]), fmaxf(sm[2], sm[3]));
        #pragma unroll
        for (int off = 1; off < 16; off <<= 1) mx = fmaxf(mx, __shfl_xor(mx, off));
        const float Mn = fmaxf(M[rt][r], mx);
        const float al = __expf(M[rt][r] - Mn);
        M[rt][r] = Mn;
        float p[4], rs = 0.f;
        #pragma unroll
        for (int j = 0; j < 4; j++){ p[j] = __expf(sm[j] - Mn); rs += p[j]; }
        #pragma unroll
        for (int off = 1; off < 16; off <<= 1) rs += __shfl_xor(rs, off);
        l[rt][r] = l[rt][r] * al + rs;
        #pragma unroll
        for (int j = 0; j < 4; j++) acc[rt][j][r] *= al;
        const int prow = w*32 + rt*16 + lq*4 + r;
        #pragma unroll
        for (int j = 0; j < 4; j++) Ps[prow][j*16 + l16] = f2bf(p[j]);
      }
    }

    // PV: acc[rt][j] += P(rows rt) @ V  (Ps rows are wave-private; lgkmcnt only)
    #pragma unroll
    for (int ks = 0; ks < 2; ks++){
      bfrag pa0 = *(const bfrag*)&Ps[w*32 +      l16][lq*8 + 32*ks];
      bfrag pa1 = *(const bfrag*)&Ps[w*32 + 16 + l16][lq*8 + 32*ks];
      #pragma unroll
      for (int j = 0; j < 4; j++){
        bfrag vbf = *(const bfrag*)&Vt[j*16 + l16][lq*8 + 32*ks];
        acc[0][j] = __builtin_amdgcn_mfma_f32_16x16x32_bf16(pa0, vbf, acc[0][j], 0, 0, 0);
        acc[1][j] = __builtin_amdgcn_mfma_f32_16x16x32_bf16(pa1, vbf, acc[1][j], 0, 0, 0);
      }
    }
    __syncthreads();   // all waves done with Ks/Vt before restage
  }

  #pragma unroll
  for (int rt = 0; rt < 2; rt++)
    #pragma unroll
    for (int r = 0; r < 4; r++){
      const int n = row0 + w*32 + rt*16 + lq*4 + r;
      if (n < NTOK){
        const float inv = 1.0f / l[rt][r];
        #pragma unroll
        for (int j = 0; j < 4; j++){
          const size_t idx = base + (size_t)n*HD + j*16 + l16;
          float o = acc[rt][j][r] * inv;
          if (accum) o += Out[idx];
          Out[idx] = o;
        }
      }
    }
}

// ---------------------------------------------------------------------------
extern "C" void kernel_launch(void* const* d_in, const int* in_sizes, int n_in,
                              void* d_out, int out_size, void* d_ws, size_t ws_size,
                              hipStream_t stream)
{
  (void)in_sizes; (void)n_in; (void)out_size; (void)ws_size;

  const float* x     = (const float*)d_in[0];   // fp32 [N,B,C]
  const float* wqkv  = (const float*)d_in[1];   // fp32 [2304,768]
  const float* wproj = (const float*)d_in[2];   // fp32 [768,768]
  const float* bias  = (const float*)d_in[3];   // fp32 [768]
  float* out = (float*)d_out;                   // fp32: [x_out | x_ori], each [N,B,C]

  ushort_t* qb = (ushort_t*)d_ws;               // bf16 [B,H,N,hd]
  ushort_t* kb = qb + SZ;
  ushort_t* vb = kb + SZ;
  ushort_t* xh = vb + SZ;                       // bf16 scratch (normalized)
  float*  y   = (float*)(xh + SZ);              // fp32 [B,H,N,hd]
  float*  acc = y + SZ;                         // fp32 accumulator
  float*  pre = acc + SZ;                       // 8 floats

  hipMemsetAsync(pre, 0, BB * sizeof(float), stream);

  prenorm_kernel<<<dim3(50, 8), 256, 0, stream>>>(x, pre);
  qkv_gemm<<<dim3(25, 36, 8), 256, 0, stream>>>(x, wqkv, qb, kb, vb);

  const float SCALE = 0.125f;                 // hd^-0.5
  const float FACT  = SCALE / (float)NTOK;    // inv_temp = pre[b] * FACT
  const dim3 AG(13, 96);

  // original attention -> x_ori (second output)
  attn_mfma<<<AG, 256, 0, stream>>>(qb, kb, vb, y, nullptr, SCALE, 0);
  proj_gemm<<<dim3(25, 12, 8), 256, 0, stream>>>(y, wproj, bias,
      out + (size_t)NTOK * BB * CC, 1.0f);

  // self-self branches over {q, k, v}
  const ushort_t* srcs[3] = { qb, kb, vb };
  for (int sI = 0; sI < 3; sI++){
    l2norm_kernel<<<(NVEC + 7) / 8, 256, 0, stream>>>(srcs[sI], nullptr, xh);
    attn_mfma<<<AG, 256, 0, stream>>>(xh, xh, xh, y, pre, FACT, 0);
    l2norm_kernel<<<(NVEC + 7) / 8, 256, 0, stream>>>(nullptr, y, xh);
    attn_mfma<<<AG, 256, 0, stream>>>(xh, xh, vb, acc, pre, FACT, sI == 0 ? 0 : 1);
  }

  // (sum of branches)/3 -> proj -> x_out (first output)
  proj_gemm<<<dim3(25, 12, 8), 256, 0, stream>>>(acc, wproj, bias, out, 1.0f / 3.0f);
}

// Round 4
// 1390.538 us; speedup vs baseline: 5.1546x; 1.6244x over previous
//
#include <hip/hip_runtime.h>
#include <stdint.h>

#define NTOK 1569
#define BB 8
#define CC 768
#define HH 12
#define HD 64
#define NBH (BB*HH)          // 96
#define NROW (NTOK*BB)       // 12552 rows of the [N*B][768] matrices
#define NCHUNK 25            // ceil(1569/64) key chunks
#define NVEC (NBH*NTOK)      // 150624 head-vectors
#define LASTV 33             // valid keys in last chunk: 1569 - 24*64

typedef unsigned short ushort_t;
static const size_t SZ = (size_t)NROW * CC;   // 9,639,936 elems (= NBH*NTOK*HD)

using f32x4 = __attribute__((ext_vector_type(4))) float;
using i32x4 = __attribute__((ext_vector_type(4))) int;
using i32x2 = __attribute__((ext_vector_type(2))) int;
using hfrag = __attribute__((ext_vector_type(8))) _Float16;

// ---------------------------------------------------------------------------
// pre[b] = sum_n ||x[n,b,:]||_2  (fp32 input)
// ---------------------------------------------------------------------------
__global__ __launch_bounds__(256) void prenorm_kernel(const float* __restrict__ x,
                                                      float* __restrict__ pre)
{
  const int b = blockIdx.y;
  const int wave = threadIdx.x >> 6, lane = threadIdx.x & 63;
  const int g = blockIdx.x * 4 + wave;          // [0, 200)
  float local = 0.f;
  for (int n = g; n < NTOK; n += 200){
    const float* xp = x + ((size_t)n * BB + b) * CC + lane * 4;
    float ss = 0.f;
    #pragma unroll
    for (int e = 0; e < 3; e++){
      f32x4 vv = *(const f32x4*)(xp + 256*e);
      ss += vv[0]*vv[0] + vv[1]*vv[1] + vv[2]*vv[2] + vv[3]*vv[3];
    }
    #pragma unroll
    for (int off = 1; off < 64; off <<= 1) ss += __shfl_xor(ss, off);
    local += sqrtf(ss);
  }
  if (lane == 0) atomicAdd(&pre[b], local);
}

// ---------------------------------------------------------------------------
// elementwise fp32 -> f16 (RTN), optional scale; n8 = elems/8
// ---------------------------------------------------------------------------
__global__ __launch_bounds__(256) void cvt_f16(const float* __restrict__ in,
                                               ushort_t* __restrict__ out,
                                               int n8, float scl)
{
  const int i = blockIdx.x * 256 + threadIdx.x;
  if (i >= n8) return;
  const float* p = in + (size_t)i * 8;
  f32x4 a = *(const f32x4*)p, b = *(const f32x4*)(p + 4);
  union { _Float16 h[8]; i32x4 v; } u;
  #pragma unroll
  for (int e = 0; e < 4; e++){
    u.h[e]   = (_Float16)(a[e] * scl);
    u.h[4+e] = (_Float16)(b[e] * scl);
  }
  *(i32x4*)(out + (size_t)i * 8) = u.v;
}

// ---------------------------------------------------------------------------
// f16 GEMM: C[m][j] = sum_c A[m][c] * B[j][c];  A [12552][768], B [Nj][768].
// 128x128 tile, BK=64, LDS layout [rowblk][kq][row16][8] (2-way max conflicts).
// mode 0: scatter f16 to q/k/v [B,H,N,64] (Nj=2304)
// mode 1: fp32 out[m*768 + j] + bias[j]       (Nj=768)
// grid: (99, Nj/128), block 256
// ---------------------------------------------------------------------------
__global__ __launch_bounds__(256) void gemm768(
    const ushort_t* __restrict__ A, const ushort_t* __restrict__ Bm,
    ushort_t* __restrict__ q, ushort_t* __restrict__ k, ushort_t* __restrict__ v,
    float* __restrict__ outp, const float* __restrict__ bias, int mode)
{
  __shared__ __align__(16) ushort_t As[8192];  // [rb 0..7][kq 0..7][r16 0..15][8]
  __shared__ __align__(16) ushort_t Bs[8192];

  const int mt = blockIdx.x, jt = blockIdx.y;
  const int tid = threadIdx.x;
  const int w = tid >> 6, lane = tid & 63;
  const int l16 = lane & 15, lq = lane >> 4;

  const int srow = tid & 127, shalf = tid >> 7;       // staging: row + col-half
  int ga = mt*128 + srow; if (ga > NROW-1) ga = NROW-1;
  const ushort_t* ap = A  + (size_t)ga * CC + shalf*32;
  const ushort_t* bp = Bm + (size_t)(jt*128 + srow) * CC + shalf*32;
  const int rb = srow >> 4, r16 = srow & 15;

  const int wr = (w >> 1) * 4, wc = (w & 1) * 4;      // 16-row/col block bases

  f32x4 acc[4][4] = {};
  for (int kt = 0; kt < 12; kt++){
    #pragma unroll
    for (int i = 0; i < 4; i++){
      const int kq = shalf*4 + i;
      *(i32x4*)&As[((rb*8 + kq)*16 + r16)*8] = *(const i32x4*)(ap + kt*64 + i*8);
      *(i32x4*)&Bs[((rb*8 + kq)*16 + r16)*8] = *(const i32x4*)(bp + kt*64 + i*8);
    }
    __syncthreads();
    #pragma unroll
    for (int ks = 0; ks < 2; ks++){
      hfrag af[4], bf[4];
      #pragma unroll
      for (int rt = 0; rt < 4; rt++)
        af[rt] = *(const hfrag*)&As[(((wr+rt)*8 + ks*4 + lq)*16 + l16)*8];
      #pragma unroll
      for (int ct = 0; ct < 4; ct++)
        bf[ct] = *(const hfrag*)&Bs[(((wc+ct)*8 + ks*4 + lq)*16 + l16)*8];
      #pragma unroll
      for (int rt = 0; rt < 4; rt++)
        #pragma unroll
        for (int ct = 0; ct < 4; ct++)
          acc[rt][ct] = __builtin_amdgcn_mfma_f32_16x16x32_f16(af[rt], bf[ct], acc[rt][ct], 0, 0, 0);
    }
    __syncthreads();
  }

  const int mbase = mt*128 + (w >> 1)*64;
  const int jbase = jt*128 + (w & 1)*64;
  #pragma unroll
  for (int ct = 0; ct < 4; ct++){
    const int j = jbase + ct*16 + l16;
    if (mode == 0){
      const int s = j / 768, jj = j - s*768;
      const int h = jj >> 6, d = jj & 63;
      ushort_t* op = (s == 0) ? q : (s == 1) ? k : v;
      const size_t obase = ((size_t)(0*12 + h)) * 0;  // placeholder to keep structure
      (void)obase;
      #pragma unroll
      for (int rt = 0; rt < 4; rt++)
        #pragma unroll
        for (int r = 0; r < 4; r++){
          const int m = mbase + rt*16 + lq*4 + r;
          if (m < NROW){
            const int n = m >> 3, b = m & 7;
            union { _Float16 h16; ushort_t u; } cv;
            cv.h16 = (_Float16)acc[rt][ct][r];
            op[((size_t)(b*HH + h) * NTOK + n) * HD + d] = cv.u;
          }
        }
    } else {
      const float bv = bias[j];
      #pragma unroll
      for (int rt = 0; rt < 4; rt++)
        #pragma unroll
        for (int r = 0; r < 4; r++){
          const int m = mbase + rt*16 + lq*4 + r;
          if (m < NROW) outp[(size_t)m * CC + j] = acc[rt][ct][r] + bv;
        }
    }
  }
}

// ---------------------------------------------------------------------------
// l2 normalize per head-vector (64 elems), 32 lanes/vector, f16 in/out.
// mode 0: in is [B,H,N,64];  mode 1: in is row-768 layout [(n*8+b)][h*64+d]
// out: [B,H,N,64]
// ---------------------------------------------------------------------------
__global__ __launch_bounds__(256) void l2norm_kernel(const ushort_t* __restrict__ in,
                                                     ushort_t* __restrict__ out,
                                                     int mode)
{
  const int vec = blockIdx.x * 8 + (threadIdx.x >> 5);
  const int lane = threadIdx.x & 31;
  if (vec >= NVEC) return;
  size_t iaddr;
  if (mode == 0){
    iaddr = (size_t)vec * HD + lane*2;
  } else {
    const int b = vec / (HH*NTOK);
    const int rem = vec - b*(HH*NTOK);
    const int h = rem / NTOK, n = rem - h*NTOK;
    iaddr = (size_t)(n*BB + b) * CC + h*HD + lane*2;
  }
  union { ushort_t u[2]; uint32_t pk; _Float16 h[2]; } uv;
  uv.pk = *(const uint32_t*)(in + iaddr);
  const float a = (float)uv.h[0], c = (float)uv.h[1];
  float ss = a*a + c*c;
  #pragma unroll
  for (int off = 1; off < 32; off <<= 1) ss += __shfl_xor(ss, off);
  const float inv = 1.0f / fmaxf(sqrtf(ss), 1e-12f);
  union { _Float16 h[2]; uint32_t pk; } ov;
  ov.h[0] = (_Float16)(a * inv);
  ov.h[1] = (_Float16)(c * inv);
  *(uint32_t*)(out + (size_t)vec * HD + lane*2) = ov.pk;
}

// ---------------------------------------------------------------------------
// MFMA flash attention, transposed-S, max-free softmax (logits provably small).
// X,Y,Z f16 [B,H,N,64]. 128 queries/block (4 waves x 32), 64-key chunks.
// S^T = K·Q^T (C rows=keys -> key-reduction is lane-local); P -> LDS packed
// b64; PV with V^T tiles. Row-sum deferred to epilogue (no per-chunk shuffles,
// no max tracking, no alpha rescale).
// mode 0: f16 out, row-768 layout. mode 1: fp32 (+=) row-768 layout.
// LDS: Ks[64][72]+Vt[64][72]+Pt[128][72] f16 = 36 KB.  grid: (13, 96)
// ---------------------------------------------------------------------------
__global__ __launch_bounds__(256) void attn_mfma(
    const ushort_t* __restrict__ X, const ushort_t* __restrict__ Y,
    const ushort_t* __restrict__ Z, void* __restrict__ outp,
    const float* __restrict__ pre, float tf, int mode, int accum)
{
  __shared__ __align__(16) ushort_t Ks[64][72];
  __shared__ __align__(16) ushort_t Vt[64][72];
  __shared__ __align__(16) ushort_t Pt[128][72];

  const int bh = blockIdx.y, b = bh / HH, h = bh % HH;
  const float temp = pre ? pre[b] * tf : tf;
  const size_t base = (size_t)bh * NTOK * HD;
  const int row0 = blockIdx.x * 128;
  const int tid = threadIdx.x;
  const int w = tid >> 6, lane = tid & 63;
  const int l16 = lane & 15, lq = lane >> 4;

  // Q fragments (b-operand of S^T): rows row0 + w*32 + qt*16 + l16
  hfrag qf[2][2];
  #pragma unroll
  for (int qt = 0; qt < 2; qt++){
    int r = row0 + w*32 + qt*16 + l16; if (r > NTOK-1) r = NTOK-1;
    const ushort_t* qp = X + base + (size_t)r*HD + lq*8;
    qf[qt][0] = *(const hfrag*)qp;
    qf[qt][1] = *(const hfrag*)(qp + 32);
  }

  // staging maps
  const int skey = tid & 63, sseg = tid >> 6;              // K natural
  const int vd0 = ((tid >> 3) & 7) * 8;                    // V^T: 8 d-rows
  const int vk0 = (tid & 7) * 2 + (tid >> 6) * 16;         //      2 keys

  f32x4 acc[2][4] = {};     // [qt][dt4], rows=queries(4lq+r), cols=d(l16)
  float lsum[2] = {0.f, 0.f};

  for (int ch = 0; ch < NCHUNK; ch++){
    { // stage K (natural) and V (transposed, key-pairs packed)
      int kg = ch*64 + skey; if (kg > NTOK-1) kg = NTOK-1;
      const ushort_t* kp = Y + base + (size_t)kg*HD + sseg*16;
      *(i32x4*)&Ks[skey][sseg*16]     = *(const i32x4*)kp;
      *(i32x4*)&Ks[skey][sseg*16 + 8] = *(const i32x4*)(kp + 8);

      int vg0 = ch*64 + vk0, vg1 = vg0 + 1;
      if (vg0 > NTOK-1) vg0 = NTOK-1;
      if (vg1 > NTOK-1) vg1 = NTOK-1;
      union { ushort_t s[8]; i32x4 v; } za, zb;
      za.v = *(const i32x4*)(Z + base + (size_t)vg0*HD + vd0);
      zb.v = *(const i32x4*)(Z + base + (size_t)vg1*HD + vd0);
      #pragma unroll
      for (int e = 0; e < 8; e++)
        *(uint32_t*)&Vt[vd0 + e][vk0] = (uint32_t)za.s[e] | ((uint32_t)zb.s[e] << 16);
    }
    __syncthreads();

    // S^T = K·Q^T : s[kt4][qt], rows=keys kt4*16+4lq+r, cols=queries qt*16+l16
    f32x4 s[4][2] = {};
    #pragma unroll
    for (int ks = 0; ks < 2; ks++){
      #pragma unroll
      for (int kt4 = 0; kt4 < 4; kt4++){
        hfrag kf = *(const hfrag*)&Ks[kt4*16 + l16][ks*32 + lq*8];
        s[kt4][0] = __builtin_amdgcn_mfma_f32_16x16x32_f16(kf, qf[0][ks], s[kt4][0], 0, 0, 0);
        s[kt4][1] = __builtin_amdgcn_mfma_f32_16x16x32_f16(kf, qf[1][ks], s[kt4][1], 0, 0, 0);
      }
    }

    // p = exp(s*temp); mask tail keys in last chunk; accumulate row-sums
    const bool lastch = (ch == NCHUNK-1);
    #pragma unroll
    for (int kt4 = 0; kt4 < 4; kt4++){
      const int kb = kt4*16 + lq*4;
      #pragma unroll
      for (int qt = 0; qt < 2; qt++){
        float p0 = __expf(s[kt4][qt][0] * temp);
        float p1 = __expf(s[kt4][qt][1] * temp);
        float p2 = __expf(s[kt4][qt][2] * temp);
        float p3 = __expf(s[kt4][qt][3] * temp);
        if (lastch){
          if (kb + 0 >= LASTV) p0 = 0.f;
          if (kb + 1 >= LASTV) p1 = 0.f;
          if (kb + 2 >= LASTV) p2 = 0.f;
          if (kb + 3 >= LASTV) p3 = 0.f;
        }
        lsum[qt] += p0 + p1 + p2 + p3;
        union { _Float16 h[4]; i32x2 v2; } pw;
        pw.h[0] = (_Float16)p0; pw.h[1] = (_Float16)p1;
        pw.h[2] = (_Float16)p2; pw.h[3] = (_Float16)p3;
        *(i32x2*)&Pt[w*32 + qt*16 + l16][kb] = pw.v2;
      }
    }

    // PV: acc[qt][dt4] += P(queries) @ V   (Pt rows are wave-private)
    #pragma unroll
    for (int ks = 0; ks < 2; ks++){
      hfrag pa0 = *(const hfrag*)&Pt[w*32 +      l16][ks*32 + lq*8];
      hfrag pa1 = *(const hfrag*)&Pt[w*32 + 16 + l16][ks*32 + lq*8];
      #pragma unroll
      for (int dt4 = 0; dt4 < 4; dt4++){
        hfrag vf = *(const hfrag*)&Vt[dt4*16 + l16][ks*32 + lq*8];
        acc[0][dt4] = __builtin_amdgcn_mfma_f32_16x16x32_f16(pa0, vf, acc[0][dt4], 0, 0, 0);
        acc[1][dt4] = __builtin_amdgcn_mfma_f32_16x16x32_f16(pa1, vf, acc[1][dt4], 0, 0, 0);
      }
    }
    __syncthreads();
  }

  // final row sums: reduce over lq groups, then redistribute to C-row owners
  float lfin[2];
  #pragma unroll
  for (int qt = 0; qt < 2; qt++){
    float lt = lsum[qt];
    lt += __shfl_xor(lt, 16);
    lt += __shfl_xor(lt, 32);
    lfin[qt] = lt;   // full sum for query qt*16+l16 (replicated across lq)
  }

  #pragma unroll
  for (int qt = 0; qt < 2; qt++)
    #pragma unroll
    for (int r = 0; r < 4; r++){
      const float lv = __int_as_float(
          __builtin_amdgcn_ds_bpermute((lq*4 + r) * 4, __float_as_int(lfin[qt])));
      const int n = row0 + w*32 + qt*16 + lq*4 + r;
      if (n < NTOK){
        const float inv = 1.0f / lv;
        const size_t rbase = (size_t)(n*BB + b) * CC + h*HD;
        if (mode == 0){
          ushort_t* yo = (ushort_t*)outp;
          #pragma unroll
          for (int dt4 = 0; dt4 < 4; dt4++){
            union { _Float16 h16; ushort_t u; } cv;
            cv.h16 = (_Float16)(acc[qt][dt4][r] * inv);
            yo[rbase + dt4*16 + l16] = cv.u;
          }
        } else {
          float* ao = (float*)outp;
          #pragma unroll
          for (int dt4 = 0; dt4 < 4; dt4++){
            float o = acc[qt][dt4][r] * inv;
            if (accum) o += ao[rbase + dt4*16 + l16];
            ao[rbase + dt4*16 + l16] = o;
          }
        }
      }
    }
}

// ---------------------------------------------------------------------------
extern "C" void kernel_launch(void* const* d_in, const int* in_sizes, int n_in,
                              void* d_out, int out_size, void* d_ws, size_t ws_size,
                              hipStream_t stream)
{
  (void)in_sizes; (void)n_in; (void)out_size; (void)ws_size;

  const float* x     = (const float*)d_in[0];   // fp32 [N,B,C]
  const float* wqkv  = (const float*)d_in[1];   // fp32 [2304,768]
  const float* wproj = (const float*)d_in[2];   // fp32 [768,768]
  const float* bias  = (const float*)d_in[3];   // fp32 [768]
  float* out = (float*)d_out;                   // fp32: [x_out | x_ori]

  ushort_t* x16  = (ushort_t*)d_ws;             // f16 [12552][768]
  ushort_t* wq16 = x16 + SZ;                    // f16 [2304][768]
  ushort_t* wp16 = wq16 + (size_t)2304*768;     // f16 [768][768]
  ushort_t* qb   = wp16 + (size_t)768*768;      // f16 [B,H,N,64] x3
  ushort_t* kb   = qb + SZ;
  ushort_t* vb   = kb + SZ;
  ushort_t* xh   = vb + SZ;                     // f16 [B,H,N,64] scratch
  ushort_t* y16  = xh + SZ;                     // f16 row-768 scratch (also acc16)
  float*    acc  = (float*)(y16 + SZ);          // fp32 row-768 accumulator
  float*    pre  = acc + SZ;                    // 8 floats

  hipMemsetAsync(pre, 0, BB * sizeof(float), stream);

  cvt_f16<<<(int)(SZ/8 + 255)/256, 256, 0, stream>>>(x, x16, (int)(SZ/8), 1.0f);
  cvt_f16<<<(2304*768/8 + 255)/256, 256, 0, stream>>>(wqkv, wq16, 2304*768/8, 1.0f);
  cvt_f16<<<(768*768/8 + 255)/256, 256, 0, stream>>>(wproj, wp16, 768*768/8, 1.0f);
  prenorm_kernel<<<dim3(50, 8), 256, 0, stream>>>(x, pre);

  gemm768<<<dim3(99, 18), 256, 0, stream>>>(x16, wq16, qb, kb, vb, nullptr, nullptr, 0);

  const float SCALE = 0.125f;                 // hd^-0.5
  const float FACT  = SCALE / (float)NTOK;    // inv_temp = pre[b] * FACT
  const dim3 AG(13, 96);

  // original attention -> x_ori (second output)
  attn_mfma<<<AG, 256, 0, stream>>>(qb, kb, vb, y16, nullptr, SCALE, 0, 0);
  gemm768<<<dim3(99, 6), 256, 0, stream>>>(y16, wp16, nullptr, nullptr, nullptr,
      out + (size_t)NTOK * BB * CC, bias, 1);

  // self-self branches over {q, k, v}
  const ushort_t* srcs[3] = { qb, kb, vb };
  for (int sI = 0; sI < 3; sI++){
    l2norm_kernel<<<NVEC/8, 256, 0, stream>>>(srcs[sI], xh, 0);
    attn_mfma<<<AG, 256, 0, stream>>>(xh, xh, xh, y16, pre, FACT, 0, 0);
    l2norm_kernel<<<NVEC/8, 256, 0, stream>>>(y16, xh, 1);
    attn_mfma<<<AG, 256, 0, stream>>>(xh, xh, vb, acc, pre, FACT, 1, sI == 0 ? 0 : 1);
  }

  // (sum/3) -> f16 (reuse y16) -> proj -> x_out (first output)
  cvt_f16<<<(int)(SZ/8 + 255)/256, 256, 0, stream>>>(acc, y16, (int)(SZ/8), 1.0f/3.0f);
  gemm768<<<dim3(99, 6), 256, 0, stream>>>(y16, wp16, nullptr, nullptr, nullptr,
      out, bias, 1);
}